// Round 3
// baseline (324.523 us; speedup 1.0000x reference)
//
#include <hip/hip_runtime.h>

#define N_ROWS   1048576
#define T_COLS   32
#define NBLK     512
#define BLOCK    1024
#define WAVES    16
#define ROWS_PER_WAVE 256
#define CH       16                 // 16-row chunks per wave (256 rows / wave)
#define NWS      2080               // 1024 Gt + 1024 Gp + 32 colsums
#define NREP     64                 // replicated accumulation slots in ws

typedef _Float16 half8    __attribute__((ext_vector_type(8)));
typedef float    floatx16 __attribute__((ext_vector_type(16)));

// Per-wave LDS: double-buffered 16x32 f32 chunk (2 KB each).
// global_load_lds width=16: lane l -> LDS base + l*16 == row (l>>3), cols (l&7)*4..+3
// -> linear row-major [16][32] f32, written by 2 DMA instructions per chunk.
#define CHUNK_BYTES 2048
#define WAVE_BYTES  (2 * CHUNK_BYTES)
#define LDS_BYTES   (WAVES * WAVE_BYTES)   // 64 KiB; s_red (8320 B) overlays after loop

// Gram via mfma_f32_32x32x16_f16 with the SAME fragment as A and B (A/B lane
// maps identical: dim=lane&31, k=(lane>>5)*8+elem; any within-lane k-perm
// cancels A vs B; C/D transposition harmless since G is symmetric).
__global__ __launch_bounds__(BLOCK, 8) void ts_gram(const float* __restrict__ y_pred,
                                                    const float* __restrict__ y_true,
                                                    float* __restrict__ ws) {
    __shared__ alignas(16) char smem[LDS_BYTES];

    const int tid  = threadIdx.x;
    const int wv   = tid >> 6;
    const int mtx  = wv >> 3;          // 0 = y_true (waves 0-7), 1 = y_pred (waves 8-15)
    const int sub  = wv & 7;
    const int lane = tid & 63;
    const int hi   = lane >> 5;        // k-half within chunk (MFMA frag)
    const int col  = lane & 31;        // MFMA frag column

    const float* src = (mtx == 0) ? y_true : y_pred;
    const size_t row0 = (size_t)blockIdx.x * (8 * ROWS_PER_WAVE) + (size_t)sub * ROWS_PER_WAVE;
    // per-lane DMA source: row = row0 + (lane>>3) [+ chunk*16 + q*8], cols (lane&7)*4..+3
    const float* gp = src + (row0 + (size_t)(lane >> 3)) * T_COLS + (lane & 7) * 4;

    char* lbase = smem + wv * WAVE_BYTES;   // wave-private: no barriers in loop

#define ISSUE(c) do {                                                         \
        char* lb_ = lbase + (((c) & 1) * CHUNK_BYTES);                        \
        const float* g_ = gp + (size_t)((c) * 16) * T_COLS;                   \
        __builtin_amdgcn_global_load_lds(                                     \
            (const __attribute__((address_space(1))) void*)g_,                \
            (__attribute__((address_space(3))) void*)lb_, 16, 0, 0);          \
        __builtin_amdgcn_global_load_lds(                                     \
            (const __attribute__((address_space(1))) void*)(g_ + 8 * T_COLS), \
            (__attribute__((address_space(3))) void*)(lb_ + 1024), 16, 0, 0); \
    } while (0)

    floatx16 acc = {};
    float cs = 0.0f;

    ISSUE(0);
    ISSUE(1);

    #pragma unroll
    for (int c = 0; c < CH; ++c) {
        // chunk c must be resident; chunk c+1's 2 loads may stay in flight
        if (c + 1 < CH) { asm volatile("s_waitcnt vmcnt(2)" ::: "memory"); }
        else            { asm volatile("s_waitcnt vmcnt(0)" ::: "memory"); }
        __builtin_amdgcn_sched_barrier(0);

        // frag read: lds[hi*8+j][col] -> bank=col, 2 lanes/bank = conflict-free
        const float* rp = (const float*)(lbase + (c & 1) * CHUNK_BYTES)
                          + (size_t)hi * 8 * T_COLS + col;
        float v[8];
        #pragma unroll
        for (int j = 0; j < 8; ++j) v[j] = rp[j * T_COLS];

        // values in VGPRs before the DMA below overwrites this buffer
        asm volatile("s_waitcnt lgkmcnt(0)" ::: "memory");
        __builtin_amdgcn_sched_barrier(0);
        if (c + 2 < CH) ISSUE(c + 2);

        half8 h;
        #pragma unroll
        for (int j = 0; j < 8; ++j) h[j] = (_Float16)v[j];
        if (mtx == 0) {                 // wave-uniform branch; colsum in fp32
            #pragma unroll
            for (int j = 0; j < 8; ++j) cs += v[j];
        }
        acc = __builtin_amdgcn_mfma_f32_32x32x16_f16(h, h, acc, 0, 0, 0);
    }
#undef ISSUE

    // ---- block reduction (s_red overlays staging LDS; all DMA drained) ----
    __syncthreads();
    float* s_red = (float*)smem;
    for (int i = tid; i < NWS; i += BLOCK) s_red[i] = 0.0f;
    __syncthreads();
    // C/D layout (m74/m101, dtype-independent): col=lane&31,
    // row=(r&3)+8*(r>>2)+4*(lane>>5). 8-way collisions (sub 0..7).
    #pragma unroll
    for (int r = 0; r < 16; ++r) {
        int row = (r & 3) + 8 * (r >> 2) + 4 * hi;
        atomicAdd(&s_red[mtx * 1024 + row * 32 + col], acc[r]);
    }
    if (mtx == 0) {
        // lane holds column-col partial sum over its hi-half rows
        cs += __shfl_xor(cs, 32);
        if (lane < 32) atomicAdd(&s_red[2048 + col], cs);   // 8-way collisions
    }
    __syncthreads();
    // replica slot spreads contention: 8 blocks per address instead of 1024,
    // hot lines spread 130 -> 8320 across L2 channels
    float* wsr = ws + (size_t)(blockIdx.x & (NREP - 1)) * NWS;
    for (int i = tid; i < NWS; i += BLOCK) atomicAdd(&wsr[i], s_red[i]);
}

__global__ __launch_bounds__(1024) void ts_final(const float* __restrict__ w,
                                                 float* __restrict__ out) {
    __shared__ float s_w[NWS];
    __shared__ float s_S[32], s_nx[32], s_pn[32];
    __shared__ float s_red[16];
    const int tid = threadIdx.x;
    const float invN = 1.0f / (float)N_ROWS;

    // sum the NREP replica slots (coalesced: consecutive tid -> consecutive addr)
    for (int i = tid; i < NWS; i += 1024) {
        float t = 0.0f;
        #pragma unroll 4
        for (int r = 0; r < NREP; ++r) t += w[(size_t)r * NWS + i];
        s_w[i] = t;
    }
    __syncthreads();

    if (tid < 32) {
        float S = s_w[2048 + tid];
        s_S[tid] = S;
        float d = s_w[tid * 32 + tid] - S * S * invN;   // centered diag
        s_nx[tid] = sqrtf(d);
        s_pn[tid] = sqrtf(s_w[1024 + tid * 33]);
    }
    __syncthreads();

    const int j = tid >> 5, k = tid & 31;
    float contrib = 0.0f;
    if (j >= 1 && k > j && j < 32) {
        float gc  = s_w[j * 32 + k] - s_S[j] * s_S[k] * invN;
        float pcc = gc / (s_nx[j] * s_nx[k]);
        float cs  = s_w[1024 + j * 32 + k] / fmaxf(s_pn[j] * s_pn[k], 1e-8f);
        if (pcc >= 0.0f) contrib = 1.0f - cs;
    }
    #pragma unroll
    for (int off = 32; off > 0; off >>= 1) contrib += __shfl_down(contrib, off);
    if ((tid & 63) == 0) s_red[tid >> 6] = contrib;
    __syncthreads();
    if (tid == 0) {
        float tot = 0.0f;
        #pragma unroll
        for (int i = 0; i < 16; ++i) tot += s_red[i];
        out[0] = tot * (1.0f / 465.0f);   // c = (T-1)(T-2)/2
    }
}

extern "C" void kernel_launch(void* const* d_in, const int* in_sizes, int n_in,
                              void* d_out, int out_size, void* d_ws, size_t ws_size,
                              hipStream_t stream) {
    const float* y_pred = (const float*)d_in[0];
    const float* y_true = (const float*)d_in[1];
    float* out = (float*)d_out;
    float* ws  = (float*)d_ws;

    hipMemsetAsync(ws, 0, (size_t)NREP * NWS * sizeof(float), stream);
    ts_gram<<<NBLK, BLOCK, 0, stream>>>(y_pred, y_true, ws);
    ts_final<<<1, 1024, 0, stream>>>(ws, out);
}